// Round 1
// 1639.482 us; speedup vs baseline: 1.3443x; 1.3443x over previous
//
#include <hip/hip_runtime.h>

// Residual VQ: B=32, D=64, L=4096, NCB=4, K=512.
// out: z_q_aggregated [B][NCB][D][L] f32, then indices [B][L][NCB] (as f32).
//
// Bit-exact reproduction of the reference float32 pipeline (validated absmax=0):
//   dot[t][k]: single-accumulator FMA chain, d ascending 0..63
//   sx, se:    numpy pairwise 8-accumulator sum of squares, exact bracketing
//   d2 = (sx - 2*dot) + se     (two f32 roundings; 2*dot exact)
//   argmin:    first minimum (lowest k)
//   cascade:   x_res -= e[idx]; z_q += e[idx] in plain f32
//
// v2 structure: 32 tokens/block (8/wave), ebuf[dd][k'] transposed layout with
// lane owning 4 contiguous k's -> ds_read_b128 per dd; x_lds[d][tok] -> float4
// broadcast reads; lane-parallel pairwise sx; double-buffered ebuf with
// async-stage split (issue global loads under the dd-loop), 1 barrier/stage.

#define LL   4096
#define DD   64
#define KK   512
#define NCB  4
#define TB   32      // tokens per block
#define NTHR 256     // 4 waves; wave w owns tokens w*8..w*8+7
#define XS   36      // x_lds row stride (floats): 32 tokens + 4 pad
#define ES   260     // ebuf row stride (floats): 256 k' + 4 pad
#define EBUFN (16 * ES)

#define ZQ_ELEMS (32LL * NCB * DD * LL)   // 33,554,432 floats

// numpy pairwise sum of squares, n=64, exact op order (8 accumulators)
__device__ __forceinline__ float np_pairwise_sq64(const float* p) {
#pragma clang fp contract(off)
    float r[8];
#pragma unroll
    for (int j = 0; j < 8; ++j) { float s = p[j] * p[j]; r[j] = s; }
#pragma unroll
    for (int i = 8; i < 64; i += 8)
#pragma unroll
        for (int j = 0; j < 8; ++j) { float s = p[i + j] * p[i + j]; r[j] = r[j] + s; }
    return ((r[0] + r[1]) + (r[2] + r[3])) + ((r[4] + r[5]) + (r[6] + r[7]));
}

// ---------------- Kernel A: se[c][k] = np.sum(e*e, -1) ----------------
__global__ void se_kernel(const float* __restrict__ cb, float* __restrict__ se) {
    int t = blockIdx.x * blockDim.x + threadIdx.x;
    if (t >= NCB * KK) return;
    se[t] = np_pairwise_sq64(cb + (size_t)t * DD);
}

// ---------------- Main kernel ----------------
__global__ __launch_bounds__(NTHR, 3) void rvq_kernel(const float* __restrict__ x_in,
                                                      const float* __restrict__ cb,
                                                      const float* __restrict__ se,
                                                      float* __restrict__ out) {
    __shared__ float ebuf[2 * EBUFN];   // double-buffered codebook chunk [dd][k']
    __shared__ float x_lds[DD * XS];    // residual [d][tok]

    const int tid  = threadIdx.x;
    const int lane = tid & 63;
    const int w8   = (tid >> 6) << 3;   // wave's first token

    const long T0 = (long)blockIdx.x * TB;
    const int b  = (int)(T0 >> 12);
    const int l0 = (int)(T0 & 4095);

    // ---- stage x tile: x_lds[d][tok] = x_in[b][d][l0+tok] ----
    {
        const float* xb = x_in + (size_t)b * DD * LL + l0;
        const int dd0 = tid >> 3;
        const int t4  = (tid & 7) << 2;
#pragma unroll
        for (int it = 0; it < 2; ++it) {
            const int d = it * 32 + dd0;
            const float4 v = *reinterpret_cast<const float4*>(xb + (size_t)d * LL + t4);
            *reinterpret_cast<float4*>(&x_lds[d * XS + t4]) = v;
        }
    }

    // staging thread mapping: thread -> (d-quad sq, k' base sk)
    const int sq = tid & 3;
    const int sk = tid >> 2;

    // prefetch stage (c=0, s=0): rows k'=sk+64i, cols 0..3 within m=0 chunk
    float4 sv0, sv1, sv2, sv3;
    {
        const float* ec = cb + (size_t)(sq << 2);
        sv0 = *reinterpret_cast<const float4*>(ec + (size_t)(sk +   0) * DD);
        sv1 = *reinterpret_cast<const float4*>(ec + (size_t)(sk +  64) * DD);
        sv2 = *reinterpret_cast<const float4*>(ec + (size_t)(sk + 128) * DD);
        sv3 = *reinterpret_cast<const float4*>(ec + (size_t)(sk + 192) * DD);
    }

    __syncthreads();   // x_lds visible

    float zq[8];
#pragma unroll
    for (int t = 0; t < 8; ++t) zq[t] = 0.f;

    const int sxj = lane & 7;   // accumulator index j of pairwise sum
    const int sxt = lane >> 3;  // token (within wave) this lane-group handles

#pragma unroll 1
    for (int c = 0; c < NCB; ++c) {
        // ---- sx: lane-parallel numpy pairwise (exact bracketing via xor tree) ----
        float sxv[8];
        {
            float r;
            {
#pragma clang fp contract(off)
                float p = x_lds[sxj * XS + w8 + sxt];
                r = p * p;
#pragma unroll
                for (int i = 1; i < 8; ++i) {
                    float q = x_lds[(i * 8 + sxj) * XS + w8 + sxt];
                    r = r + q * q;
                }
            }
            // ((r0+r1)+(r2+r3)) + ((r4+r5)+(r6+r7)) at lane j=0 of each group
            float o1 = __shfl_xor(r, 1, 64);
            float a1 = r + o1;
            float o2 = __shfl_xor(a1, 2, 64);
            float a2 = a1 + o2;
            float o4 = __shfl_xor(a2, 4, 64);
            float a3 = a2 + o4;
#pragma unroll
            for (int t = 0; t < 8; ++t) sxv[t] = __shfl(a3, t << 3, 64);
        }

        float b1v[8]; int b1i[8];
#pragma unroll
        for (int t = 0; t < 8; ++t) { b1v[t] = __builtin_inff(); b1i[t] = 0; }

        float acc[8][4];   // [token][g], k = h*256 + lane*4 + g

#pragma unroll 1
        for (int s = 0; s < 8; ++s) {        // s = h*4 + m
            float* eb = &ebuf[(s & 1) * EBUFN];

            // transpose-write staged regs: eb[dd][k'] = cb[k'][m*16+dd]
            // (readers of this buffer finished before the barrier in s-1 /
            //  end-of-c barrier; lanes write consecutive k' -> conflict-free)
            eb[(sq * 4 + 0) * ES + sk      ] = sv0.x;
            eb[(sq * 4 + 1) * ES + sk      ] = sv0.y;
            eb[(sq * 4 + 2) * ES + sk      ] = sv0.z;
            eb[(sq * 4 + 3) * ES + sk      ] = sv0.w;
            eb[(sq * 4 + 0) * ES + sk +  64] = sv1.x;
            eb[(sq * 4 + 1) * ES + sk +  64] = sv1.y;
            eb[(sq * 4 + 2) * ES + sk +  64] = sv1.z;
            eb[(sq * 4 + 3) * ES + sk +  64] = sv1.w;
            eb[(sq * 4 + 0) * ES + sk + 128] = sv2.x;
            eb[(sq * 4 + 1) * ES + sk + 128] = sv2.y;
            eb[(sq * 4 + 2) * ES + sk + 128] = sv2.z;
            eb[(sq * 4 + 3) * ES + sk + 128] = sv2.w;
            eb[(sq * 4 + 0) * ES + sk + 192] = sv3.x;
            eb[(sq * 4 + 1) * ES + sk + 192] = sv3.y;
            eb[(sq * 4 + 2) * ES + sk + 192] = sv3.z;
            eb[(sq * 4 + 3) * ES + sk + 192] = sv3.w;

            __syncthreads();   // staged chunk visible to all waves

            // async-stage split: issue next chunk's global loads now; their
            // ~200cy L2 latency hides under the dd-loop below.
            {
                int nc = c, ns = s + 1;
                if (ns == 8) { nc = c + 1; ns = 0; }
                if (nc < NCB) {
                    const float* ec = cb + ((size_t)(nc * KK + (ns >> 2) * 256)) * DD
                                         + (size_t)((ns & 3) * 16 + (sq << 2));
                    sv0 = *reinterpret_cast<const float4*>(ec + (size_t)(sk +   0) * DD);
                    sv1 = *reinterpret_cast<const float4*>(ec + (size_t)(sk +  64) * DD);
                    sv2 = *reinterpret_cast<const float4*>(ec + (size_t)(sk + 128) * DD);
                    sv3 = *reinterpret_cast<const float4*>(ec + (size_t)(sk + 192) * DD);
                }
            }

            if ((s & 3) == 0) {
#pragma unroll
                for (int t = 0; t < 8; ++t)
#pragma unroll
                    for (int g = 0; g < 4; ++g) acc[t][g] = 0.f;
            }

            const int mbase = (s & 3) * 16;
#pragma unroll
            for (int dd = 0; dd < 16; ++dd) {
                const int d = mbase + dd;
                // lane's 4 contiguous k's: one ds_read_b128, conflict-free
                const float4 e4  = *reinterpret_cast<const float4*>(&eb[dd * ES + (lane << 2)]);
                // wave's 8 tokens at dim d: two broadcast float4 reads
                const float4 xa  = *reinterpret_cast<const float4*>(&x_lds[d * XS + w8]);
                const float4 xb4 = *reinterpret_cast<const float4*>(&x_lds[d * XS + w8 + 4]);
                const float xv[8] = {xa.x, xa.y, xa.z, xa.w, xb4.x, xb4.y, xb4.z, xb4.w};
                const float ev[4] = {e4.x, e4.y, e4.z, e4.w};
#pragma unroll
                for (int t = 0; t < 8; ++t)
#pragma unroll
                    for (int g = 0; g < 4; ++g)
                        acc[t][g] = fmaf(xv[t], ev[g], acc[t][g]);   // d ascending chain
            }

            if ((s & 3) == 3) {   // fold this k-half: d2 = (sx - 2*dot) + se
#pragma clang fp contract(off)
                const int kb = (s >> 2) * 256 + (lane << 2);
                const float4 se4 = *reinterpret_cast<const float4*>(&se[c * KK + kb]);
                const float sev[4] = {se4.x, se4.y, se4.z, se4.w};
#pragma unroll
                for (int t = 0; t < 8; ++t)
#pragma unroll
                    for (int g = 0; g < 4; ++g) {
                        const float twod = 2.0f * acc[t][g];      // exact (x2)
                        const float d2 = (sxv[t] - twod) + sev[g];
                        if (d2 < b1v[t]) { b1v[t] = d2; b1i[t] = kb + g; }
                    }
            }
        }

        // cross-lane argmin (butterfly), tie -> lower index (first minimum)
#pragma unroll
        for (int t = 0; t < 8; ++t) {
            float v = b1v[t]; int i = b1i[t];
#pragma unroll
            for (int off = 32; off > 0; off >>= 1) {
                const float ov = __shfl_xor(v, off, 64);
                const int   oi = __shfl_xor(i, off, 64);
                if (ov < v || (ov == v && oi < i)) { v = ov; i = oi; }
            }
            b1i[t] = i;
        }

        // residual update + z_q accumulate (wave-private columns of x_lds)
        {
#pragma clang fp contract(off)
#pragma unroll
            for (int t = 0; t < 8; ++t) {
                const float ev = cb[((size_t)(c * KK + b1i[t])) * DD + lane];
                const int xi = lane * XS + w8 + t;
                x_lds[xi] = x_lds[xi] - ev;
                zq[t] = zq[t] + ev;
            }
        }

        // indices (lane t of each wave stores its token)
#pragma unroll
        for (int t = 0; t < 8; ++t)
            if (lane == t)
                out[ZQ_ELEMS + ((size_t)b * LL + l0 + w8 + t) * NCB + c] = (float)b1i[t];

        // ---- z_q slice store via ebuf[0] alias (s=7 read buf[1]; disjoint) ----
        *reinterpret_cast<float4*>(&ebuf[lane * XS + w8])     = make_float4(zq[0], zq[1], zq[2], zq[3]);
        *reinterpret_cast<float4*>(&ebuf[lane * XS + w8 + 4]) = make_float4(zq[4], zq[5], zq[6], zq[7]);
        __syncthreads();   // zq tile visible
        {
            float* zo = out + (((size_t)b * NCB + c) * DD) * LL + l0;
            const int c4 = (tid & 7) << 2;
            const int d0 = tid >> 3;
#pragma unroll
            for (int p = 0; p < 2; ++p) {
                const int d = p * 32 + d0;
                const float4 v = *reinterpret_cast<const float4*>(&ebuf[d * XS + c4]);
                *reinterpret_cast<float4*>(zo + (size_t)d * LL + c4) = v;
            }
        }
        __syncthreads();   // zq reads done before next c's s=0 overwrites ebuf[0]
    }
}

extern "C" void kernel_launch(void* const* d_in, const int* in_sizes, int n_in,
                              void* d_out, int out_size, void* d_ws, size_t ws_size,
                              hipStream_t stream) {
    const float* x_in = (const float*)d_in[0];
    const float* cb   = (const float*)d_in[1];
    float* out = (float*)d_out;
    float* se  = (float*)d_ws;   // NCB*KK floats = 8 KB scratch

    se_kernel<<<dim3((NCB * KK + 255) / 256), dim3(256), 0, stream>>>(cb, se);
    rvq_kernel<<<dim3((32 * LL) / TB), dim3(NTHR), 0, stream>>>(x_in, cb, se, out);
}

// Round 3
// 631.385 us; speedup vs baseline: 3.4907x; 2.5966x over previous
//
#include <hip/hip_runtime.h>

// Residual VQ: B=32, D=64, L=4096, NCB=4, K=512.
// out: z_q_aggregated [B][NCB][D][L] f32, then indices [B][L][NCB] (as f32).
//
// Bit-exact reproduction of the reference float32 pipeline (validated absmax=0):
//   dot[t][k]: single-accumulator FMA chain, d ascending 0..63
//   sx, se:    numpy pairwise 8-accumulator sum of squares, exact bracketing
//   d2 = (sx - 2*dot) + se     (two f32 roundings; 2*dot exact)
//   argmin:    first minimum (lowest k)
//   cascade:   x_res -= e[idx]; z_q += e[idx] in plain f32
//
// v3: v2 structure (32 tok/block, ebuf[dd][k'] transposed staging, float4
// broadcast x reads, lane-parallel sx, double-buffered async-split prefetch)
// with the spill bug fixed: no forced min-occupancy (v2's launch_bounds(,3)
// capped VGPR at ~170 -> massive scratch spill, 6.1 GB HBM traffic), sxv
// broadcast moved into the fold (8 fewer live regs), and the residual-update /
// zq-staging lane mapping changed to (tok=lane&7, dgrp=lane>>3) which is
// bank-conflict-free (old per-lane-row mapping was 8-way: 288 = 8*36 ≡ 0 mod 32).
// v3b: fix pragma placement (must open the compound statement).

#define LL   4096
#define DD   64
#define KK   512
#define NCB  4
#define TB   32      // tokens per block
#define NTHR 256     // 4 waves; wave w owns tokens w*8..w*8+7
#define XS   36      // x_lds row stride (floats): 32 tokens + 4 pad (16B align)
#define ES   260     // ebuf row stride (floats): 256 k' + 4 pad
#define EBUFN (16 * ES)

#define ZQ_ELEMS (32LL * NCB * DD * LL)   // 33,554,432 floats

// numpy pairwise sum of squares, n=64, exact op order (8 accumulators)
__device__ __forceinline__ float np_pairwise_sq64(const float* p) {
#pragma clang fp contract(off)
    float r[8];
#pragma unroll
    for (int j = 0; j < 8; ++j) { float s = p[j] * p[j]; r[j] = s; }
#pragma unroll
    for (int i = 8; i < 64; i += 8)
#pragma unroll
        for (int j = 0; j < 8; ++j) { float s = p[i + j] * p[i + j]; r[j] = r[j] + s; }
    return ((r[0] + r[1]) + (r[2] + r[3])) + ((r[4] + r[5]) + (r[6] + r[7]));
}

// ---------------- Kernel A: se[c][k] = np.sum(e*e, -1) ----------------
__global__ void se_kernel(const float* __restrict__ cb, float* __restrict__ se) {
    int t = blockIdx.x * blockDim.x + threadIdx.x;
    if (t >= NCB * KK) return;
    se[t] = np_pairwise_sq64(cb + (size_t)t * DD);
}

// ---------------- Main kernel ----------------
__global__ __launch_bounds__(NTHR) void rvq_kernel(const float* __restrict__ x_in,
                                                   const float* __restrict__ cb,
                                                   const float* __restrict__ se,
                                                   float* __restrict__ out) {
    __shared__ float ebuf[2 * EBUFN];   // double-buffered codebook chunk [dd][k']
    __shared__ float x_lds[DD * XS];    // residual [d][tok]

    const int tid  = threadIdx.x;
    const int lane = tid & 63;
    const int w8   = (tid >> 6) << 3;   // wave's first token

    const long T0 = (long)blockIdx.x * TB;
    const int b  = (int)(T0 >> 12);
    const int l0 = (int)(T0 & 4095);

    // ---- stage x tile: x_lds[d][tok] = x_in[b][d][l0+tok] ----
    {
        const float* xb = x_in + (size_t)b * DD * LL + l0;
        const int dd0 = tid >> 3;
        const int t4  = (tid & 7) << 2;
#pragma unroll
        for (int it = 0; it < 2; ++it) {
            const int d = it * 32 + dd0;
            const float4 v = *reinterpret_cast<const float4*>(xb + (size_t)d * LL + t4);
            *reinterpret_cast<float4*>(&x_lds[d * XS + t4]) = v;
        }
    }

    // staging thread mapping: thread -> (d-quad sq, k' base sk)
    const int sq = tid & 3;
    const int sk = tid >> 2;

    // prefetch stage (c=0, s=0)
    float4 sv0, sv1, sv2, sv3;
    {
        const float* ec = cb + (size_t)(sq << 2);
        sv0 = *reinterpret_cast<const float4*>(ec + (size_t)(sk +   0) * DD);
        sv1 = *reinterpret_cast<const float4*>(ec + (size_t)(sk +  64) * DD);
        sv2 = *reinterpret_cast<const float4*>(ec + (size_t)(sk + 128) * DD);
        sv3 = *reinterpret_cast<const float4*>(ec + (size_t)(sk + 192) * DD);
    }

    __syncthreads();   // x_lds visible

    float zq[8];       // z_q[d = i*8 + (lane>>3)][tok = w8 + (lane&7)]
#pragma unroll
    for (int t = 0; t < 8; ++t) zq[t] = 0.f;

    const int sxj = lane & 7;   // accumulator index j of pairwise sum
    const int sxt = lane >> 3;  // token (within wave) this lane-group handles
    const int myt = lane & 7;   // residual-update: own token within wave
    const int da  = lane >> 3;  // residual-update: dim sub-index

#pragma unroll 1
    for (int c = 0; c < NCB; ++c) {
        // ---- sx: lane-parallel numpy pairwise (exact bracketing via xor tree) ----
        float a3;
        {
            float r;
            {
#pragma clang fp contract(off)
                float p = x_lds[sxj * XS + w8 + sxt];
                r = p * p;
#pragma unroll
                for (int i = 1; i < 8; ++i) {
                    float q = x_lds[(i * 8 + sxj) * XS + w8 + sxt];
                    r = r + q * q;
                }
            }
            // ((r0+r1)+(r2+r3)) + ((r4+r5)+(r6+r7)) for token sxt at lanes j=0
            float o1 = __shfl_xor(r, 1, 64);
            float a1 = r + o1;
            float o2 = __shfl_xor(a1, 2, 64);
            float a2 = a1 + o2;
            float o4 = __shfl_xor(a2, 4, 64);
            a3 = a2 + o4;
        }

        float b1v[8]; int b1i[8];
#pragma unroll
        for (int t = 0; t < 8; ++t) { b1v[t] = __builtin_inff(); b1i[t] = 0; }

        float acc[8][4];   // [token][g], k = h*256 + lane*4 + g

#pragma unroll 1
        for (int s = 0; s < 8; ++s) {        // s = h*4 + m
            float* eb = &ebuf[(s & 1) * EBUFN];

            // transpose-write staged regs: eb[dd][k'] = cb[k'][m*16+dd]
            eb[(sq * 4 + 0) * ES + sk      ] = sv0.x;
            eb[(sq * 4 + 1) * ES + sk      ] = sv0.y;
            eb[(sq * 4 + 2) * ES + sk      ] = sv0.z;
            eb[(sq * 4 + 3) * ES + sk      ] = sv0.w;
            eb[(sq * 4 + 0) * ES + sk +  64] = sv1.x;
            eb[(sq * 4 + 1) * ES + sk +  64] = sv1.y;
            eb[(sq * 4 + 2) * ES + sk +  64] = sv1.z;
            eb[(sq * 4 + 3) * ES + sk +  64] = sv1.w;
            eb[(sq * 4 + 0) * ES + sk + 128] = sv2.x;
            eb[(sq * 4 + 1) * ES + sk + 128] = sv2.y;
            eb[(sq * 4 + 2) * ES + sk + 128] = sv2.z;
            eb[(sq * 4 + 3) * ES + sk + 128] = sv2.w;
            eb[(sq * 4 + 0) * ES + sk + 192] = sv3.x;
            eb[(sq * 4 + 1) * ES + sk + 192] = sv3.y;
            eb[(sq * 4 + 2) * ES + sk + 192] = sv3.z;
            eb[(sq * 4 + 3) * ES + sk + 192] = sv3.w;

            __syncthreads();   // staged chunk visible to all waves

            // async-stage split: issue next chunk's global loads now; their
            // L2 latency hides under the dd-loop below.
            {
                int nc = c, ns = s + 1;
                if (ns == 8) { nc = c + 1; ns = 0; }
                if (nc < NCB) {
                    const float* ec = cb + ((size_t)(nc * KK + (ns >> 2) * 256)) * DD
                                         + (size_t)((ns & 3) * 16 + (sq << 2));
                    sv0 = *reinterpret_cast<const float4*>(ec + (size_t)(sk +   0) * DD);
                    sv1 = *reinterpret_cast<const float4*>(ec + (size_t)(sk +  64) * DD);
                    sv2 = *reinterpret_cast<const float4*>(ec + (size_t)(sk + 128) * DD);
                    sv3 = *reinterpret_cast<const float4*>(ec + (size_t)(sk + 192) * DD);
                }
            }

            if ((s & 3) == 0) {
#pragma unroll
                for (int t = 0; t < 8; ++t)
#pragma unroll
                    for (int g = 0; g < 4; ++g) acc[t][g] = 0.f;
            }

            const int mbase = (s & 3) * 16;
#pragma unroll
            for (int dd = 0; dd < 16; ++dd) {
                const int d = mbase + dd;
                // lane's 4 contiguous k's: one ds_read_b128, conflict-free
                const float4 e4  = *reinterpret_cast<const float4*>(&eb[dd * ES + (lane << 2)]);
                // wave's 8 tokens at dim d: two broadcast float4 reads
                const float4 xa  = *reinterpret_cast<const float4*>(&x_lds[d * XS + w8]);
                const float4 xb4 = *reinterpret_cast<const float4*>(&x_lds[d * XS + w8 + 4]);
                const float xv[8] = {xa.x, xa.y, xa.z, xa.w, xb4.x, xb4.y, xb4.z, xb4.w};
                const float ev[4] = {e4.x, e4.y, e4.z, e4.w};
#pragma unroll
                for (int t = 0; t < 8; ++t)
#pragma unroll
                    for (int g = 0; g < 4; ++g)
                        acc[t][g] = fmaf(xv[t], ev[g], acc[t][g]);   // d ascending chain
            }

            if ((s & 3) == 3) {   // fold this k-half: d2 = (sx - 2*dot) + se
#pragma clang fp contract(off)
                const int kb = (s >> 2) * 256 + (lane << 2);
                const float4 se4 = *reinterpret_cast<const float4*>(&se[c * KK + kb]);
                const float sev[4] = {se4.x, se4.y, se4.z, se4.w};
#pragma unroll
                for (int t = 0; t < 8; ++t) {
                    const float sxv = __shfl(a3, t << 3, 64);
#pragma unroll
                    for (int g = 0; g < 4; ++g) {
                        const float twod = 2.0f * acc[t][g];      // exact (x2)
                        const float d2 = (sxv - twod) + sev[g];
                        if (d2 < b1v[t]) { b1v[t] = d2; b1i[t] = kb + g; }
                    }
                }
            }
        }

        // cross-lane argmin (butterfly), tie -> lower index (first minimum)
#pragma unroll
        for (int t = 0; t < 8; ++t) {
            float v = b1v[t]; int i = b1i[t];
#pragma unroll
            for (int off = 32; off > 0; off >>= 1) {
                const float ov = __shfl_xor(v, off, 64);
                const int   oi = __shfl_xor(i, off, 64);
                if (ov < v || (ov == v && oi < i)) { v = ov; i = oi; }
            }
            b1i[t] = i;
        }

        // own token's code index (compile-time select; reg arrays can't be
        // runtime-indexed without going to scratch)
        int kown = 0;
#pragma unroll
        for (int t = 0; t < 8; ++t) if (myt == t) kown = b1i[t];

        // residual update + z_q accumulate, lane -> (tok=myt, d=i*8+da):
        // bank = 4*da + myt + w8 (mod 32) -> conflict-free
        {
#pragma clang fp contract(off)
            const float* erow = cb + ((size_t)(c * KK) + kown) * DD + da;
#pragma unroll
            for (int i = 0; i < 8; ++i) {
                const float ev = erow[i * 8];
                const int xi = (i * 8 + da) * XS + w8 + myt;
                x_lds[xi] = x_lds[xi] - ev;
                zq[i] = zq[i] + ev;
            }
        }

        // indices (lane t of each wave stores its token)
#pragma unroll
        for (int t = 0; t < 8; ++t)
            if (lane == t)
                out[ZQ_ELEMS + ((size_t)b * LL + l0 + w8 + t) * NCB + c] = (float)b1i[t];

        // ---- z_q slice store via ebuf[0] alias (s=7 read buf[1]; disjoint) ----
#pragma unroll
        for (int i = 0; i < 8; ++i)
            ebuf[(i * 8 + da) * XS + w8 + myt] = zq[i];
        __syncthreads();   // zq tile visible
        {
            float* zo = out + (((size_t)b * NCB + c) * DD) * LL + l0;
            const int c4 = (tid & 7) << 2;
            const int d0 = tid >> 3;
#pragma unroll
            for (int p = 0; p < 2; ++p) {
                const int d = p * 32 + d0;
                const float4 v = *reinterpret_cast<const float4*>(&ebuf[d * XS + c4]);
                *reinterpret_cast<float4*>(zo + (size_t)d * LL + c4) = v;
            }
        }
        __syncthreads();   // zq reads done before next c's s=0 overwrites ebuf[0]
    }
}

extern "C" void kernel_launch(void* const* d_in, const int* in_sizes, int n_in,
                              void* d_out, int out_size, void* d_ws, size_t ws_size,
                              hipStream_t stream) {
    const float* x_in = (const float*)d_in[0];
    const float* cb   = (const float*)d_in[1];
    float* out = (float*)d_out;
    float* se  = (float*)d_ws;   // NCB*KK floats = 8 KB scratch

    se_kernel<<<dim3((NCB * KK + 255) / 256), dim3(256), 0, stream>>>(cb, se);
    rvq_kernel<<<dim3((32 * LL) / TB), dim3(NTHR), 0, stream>>>(x_in, cb, se, out);
}